// Round 8
// baseline (589.892 us; speedup 1.0000x reference)
//
#include <hip/hip_runtime.h>

#define S_LEN 512
#define BSZ 8
#define NH 8
#define HD 64
#define IN_DIM 512
#define PROJ 2576   // NH*(5*HD+2)
#define SEG 322     // per-head: 5*64+2
#define AST 352     // act row stride f32: q64,k64,rk64,v64,rv64,beta,rbeta,pad -> 8 rows = 11*1024B
#define CHUNK 8
#define NCH 64      // 512/CHUNK
#define CB (CHUNK * AST * 4)  // 11264 bytes per chunk

typedef __attribute__((ext_vector_type(8))) __bf16 bf16x8;
typedef __attribute__((ext_vector_type(4))) float f32x4;

static __device__ __forceinline__ unsigned short f2bf(float f) {
  unsigned u = __float_as_uint(f);
  unsigned r = (u + 0x7fffu + ((u >> 16) & 1u)) >> 16;
  return (unsigned short)r;
}
static __device__ __forceinline__ float bf2f(unsigned short s) {
  return __uint_as_float(((unsigned)s) << 16);
}

static __device__ __forceinline__ void gl_lds16(const void* g, void* l) {
  __builtin_amdgcn_global_load_lds(
      (const __attribute__((address_space(1))) unsigned int*)g,
      (__attribute__((address_space(3))) unsigned int*)l, 16, 0, 0);
}

// ---------------- LayerNorm: x (4096x512 f32) -> normed bf16 ----------------
__global__ __launch_bounds__(256) void ln_kernel(const float* __restrict__ x,
                                                 const float* __restrict__ gamma,
                                                 const float* __restrict__ beta,
                                                 unsigned short* __restrict__ out) {
  int wave = threadIdx.x >> 6, lane = threadIdx.x & 63;
  int row = blockIdx.x * 4 + wave;
  const float* xr = x + (size_t)row * IN_DIM + lane * 8;
  float4 a = *(const float4*)xr;
  float4 b = *(const float4*)(xr + 4);
  float vals[8] = {a.x, a.y, a.z, a.w, b.x, b.y, b.z, b.w};
  float s = 0.f, ss = 0.f;
#pragma unroll
  for (int i = 0; i < 8; i++) { s += vals[i]; ss += vals[i] * vals[i]; }
#pragma unroll
  for (int o = 32; o; o >>= 1) { s += __shfl_xor(s, o); ss += __shfl_xor(ss, o); }
  float mu = s * (1.f / 512.f);
  float var = ss * (1.f / 512.f) - mu * mu;
  float rstd = rsqrtf(var + 1e-5f);
  const float* g = gamma + lane * 8;
  const float* be = beta + lane * 8;
  float4 g1 = *(const float4*)g, g2 = *(const float4*)(g + 4);
  float4 b1 = *(const float4*)be, b2 = *(const float4*)(be + 4);
  float gs[8] = {g1.x, g1.y, g1.z, g1.w, g2.x, g2.y, g2.z, g2.w};
  float bs[8] = {b1.x, b1.y, b1.z, b1.w, b2.x, b2.y, b2.z, b2.w};
  union { unsigned short u[8]; uint4 v; } pk;
#pragma unroll
  for (int i = 0; i < 8; i++) pk.u[i] = f2bf((vals[i] - mu) * rstd * gs[i] + bs[i]);
  *(uint4*)(out + (size_t)row * IN_DIM + lane * 8) = pk.v;
}

// ---------------- generic f32 -> bf16 cast ----------------
__global__ void cast_kernel(const float* __restrict__ in, unsigned short* __restrict__ out, int n) {
  int i = blockIdx.x * blockDim.x + threadIdx.x;
  int st = gridDim.x * blockDim.x;
  for (; i < n; i += st) out[i] = f2bf(in[i]);
}

// ---------------- GEMM: C[m][n] = sum_k A[m][k]*B[n][k] (both bf16, K-contig) ----------------
template <int BF16_OUT, int RESID>
__global__ __launch_bounds__(256) void gemm_bt(const unsigned short* __restrict__ A,
                                               const unsigned short* __restrict__ B,
                                               void* __restrict__ Cout,
                                               const float* __restrict__ resid,
                                               int M, int N, int K) {
  __shared__ __align__(16) unsigned short As[64][40];
  __shared__ __align__(16) unsigned short Bs[64][40];
  int tid = threadIdx.x;
  int lane = tid & 63, wave = tid >> 6;
  int m0 = blockIdx.y * 64, n0 = blockIdx.x * 64;
  int srow = tid >> 2, skq = (tid & 3) * 8;
  const unsigned short* Ap = A + (size_t)(m0 + srow) * K + skq;
  const unsigned short* Bp = B + (size_t)(n0 + srow) * K + skq;
  bool bvalid = (n0 + srow) < N;
  f32x4 zero = {0.f, 0.f, 0.f, 0.f};
  f32x4 acc[4];
#pragma unroll
  for (int nt = 0; nt < 4; nt++) acc[nt] = zero;
  int q = lane >> 4, m16 = lane & 15;
  for (int k0 = 0; k0 < K; k0 += 32) {
    uint4 av = *(const uint4*)(Ap + k0);
    uint4 bz = {0u, 0u, 0u, 0u};
    uint4 bv = bvalid ? *(const uint4*)(Bp + k0) : bz;
    *(uint4*)&As[srow][skq] = av;
    *(uint4*)&Bs[srow][skq] = bv;
    __syncthreads();
    bf16x8 af = *(const bf16x8*)&As[wave * 16 + m16][q * 8];
#pragma unroll
    for (int nt = 0; nt < 4; nt++) {
      bf16x8 bfv = *(const bf16x8*)&Bs[nt * 16 + m16][q * 8];
      acc[nt] = __builtin_amdgcn_mfma_f32_16x16x32_bf16(af, bfv, acc[nt], 0, 0, 0);
    }
    __syncthreads();
  }
  int rbase = q * 4;
#pragma unroll
  for (int nt = 0; nt < 4; nt++) {
#pragma unroll
    for (int rr = 0; rr < 4; rr++) {
      int gm = m0 + wave * 16 + rbase + rr;
      int gn = n0 + nt * 16 + m16;
      if (gn < N) {
        float v = acc[nt][rr];
        if (BF16_OUT) {
          ((unsigned short*)Cout)[(size_t)gm * N + gn] = f2bf(v);
        } else {
          float o = v;
          if (RESID) o += resid[(size_t)gm * N + gn];
          ((float*)Cout)[(size_t)gm * N + gn] = o;
        }
      }
    }
  }
}

// ---------------- parallel activations -> act stream (f32) ----------------
// One wave per (m = t*8+b, h). act[bh][t][AST]:
// [0:64) q softmax, [64:128) k softmax, [128:192) rk softmax,
// [192:256) v, [256:320) rv, [320] sig(beta), [321] sig(rbeta), [322:352) pad.
__global__ __launch_bounds__(256) void act_kernel(const unsigned short* __restrict__ qkvb,
                                                  float* __restrict__ act) {
  int gw = blockIdx.x * 4 + (threadIdx.x >> 6);
  int l = threadIdx.x & 63;
  int m = gw >> 3, hh = gw & 7;
  int t = m >> 3, b = m & 7;
  const unsigned short* src = qkvb + (size_t)m * PROJ + hh * SEG;
  float fq = bf2f(src[l]);
  float fk = bf2f(src[64 + l]);
  float fv = bf2f(src[128 + l]);
  float fr = bf2f(src[192 + l]);
  float frv = bf2f(src[256 + l]);
  float mq = fq, mk = fk, mr = fr;
#pragma unroll
  for (int o = 32; o; o >>= 1) {
    mq = fmaxf(mq, __shfl_xor(mq, o));
    mk = fmaxf(mk, __shfl_xor(mk, o));
    mr = fmaxf(mr, __shfl_xor(mr, o));
  }
  float eq = __expf(fq - mq), ek = __expf(fk - mk), er = __expf(fr - mr);
  float sq = eq, sk = ek, sr = er;
#pragma unroll
  for (int o = 32; o; o >>= 1) {
    sq += __shfl_xor(sq, o);
    sk += __shfl_xor(sk, o);
    sr += __shfl_xor(sr, o);
  }
  int bh = b * 8 + hh;
  float* dst = act + ((size_t)bh * S_LEN + t) * AST;
  dst[l] = eq * __builtin_amdgcn_rcpf(sq);
  dst[64 + l] = ek * __builtin_amdgcn_rcpf(sk);
  dst[128 + l] = er * __builtin_amdgcn_rcpf(sr);
  dst[192 + l] = fv;
  dst[256 + l] = frv;
  if (l < 2) {
    float xv = bf2f(src[320 + l]);
    dst[320 + l] = __builtin_amdgcn_rcpf(1.f + __expf(-xv));
  }
}

// ---------------- scan: async producer/consumer, rank-1 decomposed step ----------------
// Block = 128 threads = 2 waves per (b,h). Wave0 (producer): stages act chunks via
// global_load_lds, runs the delta-rule W-scan, deposits z into a 4-chunk LDS ring,
// publishes per-chunk flags. Wave1 (consumer): polls the flag once per chunk,
// runs the recurrent R-scan. Protocol byte-identical to the verified round-4 kernel.
// Step body restructured with W_t.x = W_{t-1}.x + c_t*(k_t.x):
//  - pass-1 computes BOTH matvecs (M.k and M.q / R.rk and R.eh) on the current state,
//    interleaved so each M[j] is reused; the lane-uniform dot (k.q / rk.eh) comes from
//    per-lane scalars + a 6-shfl tree issued at step top (hidden under matvec issue).
//  - z/h publish right after the vold-hsum -> coef chain; the 64-FMA rank-1 state
//    update runs AFTER, off the critical path, overlapping the next step's read issue.
__global__ __launch_bounds__(128, 1) void scan_kernel(const float* __restrict__ act,
                                                      unsigned short* __restrict__ hs) {
  int bh = blockIdx.x;
  int b = bh >> 3, hh = bh & 7;
  int tid = threadIdx.x, l = tid & 63, w = tid >> 6;

  __shared__ __align__(16) float stage[4][CHUNK * AST];
  __shared__ __align__(16) float zring[4][CHUNK][64];
  __shared__ __align__(16) float ehb[64];
  __shared__ int flags[16];  // [0]=w0done (chunks), [8]=w1done (chunks)

  volatile int* w0done = &flags[0];
  volatile int* w1done = &flags[8];

  const char* abase = (const char*)(act + (size_t)bh * S_LEN * AST);

  if (tid == 0) { flags[0] = 0; flags[8] = 0; }
  if (w) ehb[l] = 1.f;  // softmax(h0=0) numerators -> uniform
  if (w == 0) {
    // stage chunk 0
#pragma unroll
    for (int i = 0; i < 11; i++)
      gl_lds16(abase + (size_t)i * 1024 + l * 16, (char*)&stage[0][0] + i * 1024);
  }
  __syncthreads();  // flags/ehb init visible; drains wave0's chunk-0 staging too

  f32x4 M[16];
#pragma unroll
  for (int j = 0; j < 16; j++) M[j] = (f32x4){0.f, 0.f, 0.f, 0.f};
  const f32x4 z4 = {0.f, 0.f, 0.f, 0.f};

  if (w == 0) {
    // ================= producer: W-scan =================
    for (int c = 0; c < NCH; c++) {
      // back-pressure: staging into slot (c+1)&3 overwrites chunk c-3
      if (c >= 3) {
        while (*w1done < c - 2) __builtin_amdgcn_s_sleep(2);
      }
      if (c + 1 < NCH) {
        const char* nb = abase + (size_t)(c + 1) * CB;
        char* sb = (char*)&stage[(c + 1) & 3][0];
#pragma unroll
        for (int i = 0; i < 11; i++)
          gl_lds16(nb + (size_t)i * 1024 + l * 16, sb + i * 1024);
        asm volatile("s_waitcnt vmcnt(11)" ::: "memory");  // chunk c's staging done
      } else {
        asm volatile("s_waitcnt vmcnt(0)" ::: "memory");
      }
      const float* cb = &stage[c & 3][0];
      float* zc = &zring[c & 3][0][0];
#pragma unroll
      for (int s = 0; s < CHUNK; s++) {
        const float* stf = cb + s * AST;
        const f32x4* st4 = (const f32x4*)stf;
        // early: per-lane scalars; lane-uniform dot k.q via shfl tree (off-path)
        float kl = stf[64 + l], ql = stf[l];
        float cv = stf[192 + l];
        float bt = stf[320];
        float kq = kl * ql;
#pragma unroll
        for (int o = 32; o; o >>= 1) kq += __shfl_xor(kq, o);
        // pass-1: vold = M.k and zq = M.q on CURRENT M, interleaved (M[j] reused)
        f32x4 a0 = z4, a1 = z4, a2 = z4, a3 = z4;   // M.k
        f32x4 b0 = z4, b1 = z4, b2 = z4, b3 = z4;   // M.q
#pragma unroll
        for (int j = 0; j < 16; j += 4) {
          f32x4 k0 = st4[16 + j], q0 = st4[j];
          a0 += M[j] * k0;      b0 += M[j] * q0;
          f32x4 k1 = st4[17 + j], q1 = st4[j + 1];
          a1 += M[j + 1] * k1;  b1 += M[j + 1] * q1;
          f32x4 k2 = st4[18 + j], q2 = st4[j + 2];
          a2 += M[j + 2] * k2;  b2 += M[j + 2] * q2;
          f32x4 k3 = st4[19 + j], q3 = st4[j + 3];
          a3 += M[j + 3] * k3;  b3 += M[j + 3] * q3;
        }
        f32x4 vo = (a0 + a1) + (a2 + a3);
        f32x4 bo = (b0 + b1) + (b2 + b3);
        float vold = (vo.x + vo.y) + (vo.z + vo.w);
        float coef = bt * (cv - vold);
        float zq = (bo.x + bo.y) + (bo.z + bo.w);
        zc[s * 64 + l] = zq + coef * kq;  // z = W_t.q = M.q + coef*(k.q)
        // rank-1 update AFTER z publish (off critical path)
        f32x4 c4 = {coef, coef, coef, coef};
#pragma unroll
        for (int j = 0; j < 16; j++) M[j] += c4 * st4[16 + j];
      }
      asm volatile("s_waitcnt lgkmcnt(0)" ::: "memory");  // z writes retired
      *w0done = c + 1;
    }
  } else {
    // ================= consumer: R-scan =================
    unsigned short* hdst = hs + (size_t)b * 512 + hh * 64 + l;
    float ehl = 1.f;   // this lane's eh (exp(h-20); init matches ehb)
    float smn = 64.f;  // sum of eh across lanes (h0=0 -> 64 ones)
    for (int c = 0; c < NCH; c++) {
      while (*w0done < c + 1) __builtin_amdgcn_s_sleep(2);  // chunk c staged + z ready
      const float* cb = &stage[c & 3][0];
      const float* zc = &zring[c & 3][0][0];
#pragma unroll
      for (int s = 0; s < CHUNK; s++) {
        const float* stf = cb + s * AST;
        const f32x4* st4 = (const f32x4*)stf;
        // early: z + per-lane scalars; lane-uniform dot rk.eh via shfl (off-path)
        float zv = zc[s * 64 + l];
        float rkl = stf[128 + l];
        float cv = stf[256 + l];
        float rb = stf[321];
        float pr = rkl * ehl;
#pragma unroll
        for (int o = 32; o; o >>= 1) pr += __shfl_xor(pr, o);
        // pass-1: rvold = R.rk and hpe = R.eh on CURRENT R, interleaved.
        // rk reads ordered first to cover the ehb write->read turnaround.
        const f32x4* e4 = (const f32x4*)ehb;
        f32x4 a0 = z4, a1 = z4, a2 = z4, a3 = z4;   // R.rk
        f32x4 b0 = z4, b1 = z4, b2 = z4, b3 = z4;   // R.eh
#pragma unroll
        for (int j = 0; j < 16; j += 4) {
          f32x4 k0 = st4[32 + j];
          a0 += M[j] * k0;
          f32x4 k1 = st4[33 + j];
          a1 += M[j + 1] * k1;
          f32x4 k2 = st4[34 + j];
          a2 += M[j + 2] * k2;
          f32x4 k3 = st4[35 + j];
          a3 += M[j + 3] * k3;
          f32x4 e0 = e4[j], e1 = e4[j + 1], e2 = e4[j + 2], e3 = e4[j + 3];
          b0 += M[j] * e0;
          b1 += M[j + 1] * e1;
          b2 += M[j + 2] * e2;
          b3 += M[j + 3] * e3;
        }
        f32x4 vo = (a0 + a1) + (a2 + a3);
        f32x4 bo = (b0 + b1) + (b2 + b3);
        float rvold = (vo.x + vo.y) + (vo.z + vo.w);
        float rcoef = rb * (cv - rvold);
        float hpe = (bo.x + bo.y) + (bo.z + bo.w);
        float hp = hpe + rcoef * pr;  // R_t.eh = R.eh + rcoef*(rk.eh)
        float h = zv + hp * __builtin_amdgcn_rcpf(smn);
        hdst[(size_t)(c * CHUNK + s) * (BSZ * 512)] = f2bf(h);
        // shift-invariant: exp(h-20) keeps qh = eh/sum exact, guards overflow.
        // same-wave DS ordering makes ehb visible to next step's e4 reads.
        ehl = __expf(h - 20.f);
        ehb[l] = ehl;
        // next step's denominator via shfl tree (overlaps the rank-1 update below)
        smn = ehl;
#pragma unroll
        for (int o = 32; o; o >>= 1) smn += __shfl_xor(smn, o);
        // rank-1 update AFTER h publish (off critical path)
        f32x4 c4 = {rcoef, rcoef, rcoef, rcoef};
#pragma unroll
        for (int j = 0; j < 16; j++) M[j] += c4 * st4[32 + j];
      }
      asm volatile("s_waitcnt lgkmcnt(0)" ::: "memory");  // all chunk-c reads retired
      *w1done = c + 1;
    }
  }
}

extern "C" void kernel_launch(void* const* d_in, const int* in_sizes, int n_in,
                              void* d_out, int out_size, void* d_ws, size_t ws_size,
                              hipStream_t stream) {
  const float* x = (const float*)d_in[0];
  const float* W_slow = (const float*)d_in[1];
  const float* W_out = (const float*)d_in[2];
  const float* gamma = (const float*)d_in[3];
  const float* beta = (const float*)d_in[4];

  char* ws = (char*)d_ws;
  size_t off = 0;
  unsigned short* normed = (unsigned short*)(ws + off); off += (size_t)4096 * 512 * 2;
  unsigned short* Wslow_b = (unsigned short*)(ws + off); off += (size_t)PROJ * 512 * 2;
  unsigned short* Wout_b = (unsigned short*)(ws + off); off += (size_t)512 * 512 * 2;
  unsigned short* qkvb = (unsigned short*)(ws + off); off += (size_t)4096 * PROJ * 2;
  float* act = (float*)(ws + off); off += (size_t)64 * S_LEN * AST * 4;
  unsigned short* hsb = normed;  // normed is dead after gemm1; reuse for hs

  hipLaunchKernelGGL(ln_kernel, dim3(1024), dim3(256), 0, stream, x, gamma, beta, normed);
  hipLaunchKernelGGL(cast_kernel, dim3(512), dim3(256), 0, stream, W_slow, Wslow_b, PROJ * 512);
  hipLaunchKernelGGL(cast_kernel, dim3(256), dim3(256), 0, stream, W_out, Wout_b, 512 * 512);
  hipLaunchKernelGGL((gemm_bt<1, 0>), dim3((PROJ + 63) / 64, 4096 / 64), dim3(256), 0, stream,
                     normed, Wslow_b, (void*)qkvb, (const float*)nullptr, 4096, PROJ, 512);
  hipLaunchKernelGGL(act_kernel, dim3(8192), dim3(256), 0, stream, qkvb, act);
  hipLaunchKernelGGL(scan_kernel, dim3(64), dim3(128), 0, stream, act, hsb);
  hipLaunchKernelGGL((gemm_bt<0, 1>), dim3(512 / 64, 4096 / 64), dim3(256), 0, stream,
                     hsb, Wout_b, d_out, x, 4096, 512, 512);
}

// Round 10
// 490.702 us; speedup vs baseline: 1.2021x; 1.2021x over previous
//
#include <hip/hip_runtime.h>

#define S_LEN 512
#define BSZ 8
#define NH 8
#define HD 64
#define IN_DIM 512
#define PROJ 2576   // NH*(5*HD+2)
#define SEG 322     // per-head: 5*64+2
#define RST 384     // act row stride in bf16: q64,k64,rk64,v64,rv64,blog,rblog,pad -> 768B/row
#define CHUNK 8
#define NCH 64      // 512/CHUNK
#define CBB (CHUNK * RST * 2)  // 6144 bytes per chunk

typedef __attribute__((ext_vector_type(8))) __bf16 bf16x8;
typedef __attribute__((ext_vector_type(4))) float f32x4;

static __device__ __forceinline__ unsigned short f2bf(float f) {
  unsigned u = __float_as_uint(f);
  unsigned r = (u + 0x7fffu + ((u >> 16) & 1u)) >> 16;
  return (unsigned short)r;
}
static __device__ __forceinline__ float bf2f(unsigned short s) {
  return __uint_as_float(((unsigned)s) << 16);
}

// 8 bf16 (one uint4) -> 2 f32x4, 1 VALU op per element
static __device__ __forceinline__ void cvt8(uint4 w, f32x4* x, f32x4* y) {
  f32x4 a, b;
  a[0] = __uint_as_float(w.x << 16);
  a[1] = __uint_as_float(w.x & 0xffff0000u);
  a[2] = __uint_as_float(w.y << 16);
  a[3] = __uint_as_float(w.y & 0xffff0000u);
  b[0] = __uint_as_float(w.z << 16);
  b[1] = __uint_as_float(w.z & 0xffff0000u);
  b[2] = __uint_as_float(w.w << 16);
  b[3] = __uint_as_float(w.w & 0xffff0000u);
  *x = a;
  *y = b;
}

static __device__ __forceinline__ void gl_lds16(const void* g, void* l) {
  __builtin_amdgcn_global_load_lds(
      (const __attribute__((address_space(1))) unsigned int*)g,
      (__attribute__((address_space(3))) unsigned int*)l, 16, 0, 0);
}

// ---------------- LayerNorm: x (4096x512 f32) -> normed bf16 ----------------
__global__ __launch_bounds__(256) void ln_kernel(const float* __restrict__ x,
                                                 const float* __restrict__ gamma,
                                                 const float* __restrict__ beta,
                                                 unsigned short* __restrict__ out) {
  int wave = threadIdx.x >> 6, lane = threadIdx.x & 63;
  int row = blockIdx.x * 4 + wave;
  const float* xr = x + (size_t)row * IN_DIM + lane * 8;
  float4 a = *(const float4*)xr;
  float4 b = *(const float4*)(xr + 4);
  float vals[8] = {a.x, a.y, a.z, a.w, b.x, b.y, b.z, b.w};
  float s = 0.f, ss = 0.f;
#pragma unroll
  for (int i = 0; i < 8; i++) { s += vals[i]; ss += vals[i] * vals[i]; }
#pragma unroll
  for (int o = 32; o; o >>= 1) { s += __shfl_xor(s, o); ss += __shfl_xor(ss, o); }
  float mu = s * (1.f / 512.f);
  float var = ss * (1.f / 512.f) - mu * mu;
  float rstd = rsqrtf(var + 1e-5f);
  const float* g = gamma + lane * 8;
  const float* be = beta + lane * 8;
  float4 g1 = *(const float4*)g, g2 = *(const float4*)(g + 4);
  float4 b1 = *(const float4*)be, b2 = *(const float4*)(be + 4);
  float gs[8] = {g1.x, g1.y, g1.z, g1.w, g2.x, g2.y, g2.z, g2.w};
  float bs[8] = {b1.x, b1.y, b1.z, b1.w, b2.x, b2.y, b2.z, b2.w};
  union { unsigned short u[8]; uint4 v; } pk;
#pragma unroll
  for (int i = 0; i < 8; i++) pk.u[i] = f2bf((vals[i] - mu) * rstd * gs[i] + bs[i]);
  *(uint4*)(out + (size_t)row * IN_DIM + lane * 8) = pk.v;
}

// ---------------- generic f32 -> bf16 cast ----------------
__global__ void cast_kernel(const float* __restrict__ in, unsigned short* __restrict__ out, int n) {
  int i = blockIdx.x * blockDim.x + threadIdx.x;
  int st = gridDim.x * blockDim.x;
  for (; i < n; i += st) out[i] = f2bf(in[i]);
}

// ---------------- GEMM: C[m][n] = sum_k A[m][k]*B[n][k] (both bf16, K-contig) ----------------
template <int BF16_OUT, int RESID>
__global__ __launch_bounds__(256) void gemm_bt(const unsigned short* __restrict__ A,
                                               const unsigned short* __restrict__ B,
                                               void* __restrict__ Cout,
                                               const float* __restrict__ resid,
                                               int M, int N, int K) {
  __shared__ __align__(16) unsigned short As[64][40];
  __shared__ __align__(16) unsigned short Bs[64][40];
  int tid = threadIdx.x;
  int lane = tid & 63, wave = tid >> 6;
  int m0 = blockIdx.y * 64, n0 = blockIdx.x * 64;
  int srow = tid >> 2, skq = (tid & 3) * 8;
  const unsigned short* Ap = A + (size_t)(m0 + srow) * K + skq;
  const unsigned short* Bp = B + (size_t)(n0 + srow) * K + skq;
  bool bvalid = (n0 + srow) < N;
  f32x4 zero = {0.f, 0.f, 0.f, 0.f};
  f32x4 acc[4];
#pragma unroll
  for (int nt = 0; nt < 4; nt++) acc[nt] = zero;
  int q = lane >> 4, m16 = lane & 15;
  for (int k0 = 0; k0 < K; k0 += 32) {
    uint4 av = *(const uint4*)(Ap + k0);
    uint4 bz = {0u, 0u, 0u, 0u};
    uint4 bv = bvalid ? *(const uint4*)(Bp + k0) : bz;
    *(uint4*)&As[srow][skq] = av;
    *(uint4*)&Bs[srow][skq] = bv;
    __syncthreads();
    bf16x8 af = *(const bf16x8*)&As[wave * 16 + m16][q * 8];
#pragma unroll
    for (int nt = 0; nt < 4; nt++) {
      bf16x8 bfv = *(const bf16x8*)&Bs[nt * 16 + m16][q * 8];
      acc[nt] = __builtin_amdgcn_mfma_f32_16x16x32_bf16(af, bfv, acc[nt], 0, 0, 0);
    }
    __syncthreads();
  }
  int rbase = q * 4;
#pragma unroll
  for (int nt = 0; nt < 4; nt++) {
#pragma unroll
    for (int rr = 0; rr < 4; rr++) {
      int gm = m0 + wave * 16 + rbase + rr;
      int gn = n0 + nt * 16 + m16;
      if (gn < N) {
        float v = acc[nt][rr];
        if (BF16_OUT) {
          ((unsigned short*)Cout)[(size_t)gm * N + gn] = f2bf(v);
        } else {
          float o = v;
          if (RESID) o += resid[(size_t)gm * N + gn];
          ((float*)Cout)[(size_t)gm * N + gn] = o;
        }
      }
    }
  }
}

// ---------------- parallel activations -> act stream (bf16) ----------------
// One wave per (m = t*8+b, h). act[bh][t][RST] (bf16):
// [0:64) q softmax, [64:128) k softmax, [128:192) rk softmax,
// [192:256) v (raw copy), [256:320) rv (raw copy),
// [320] beta logit (raw), [321] rbeta logit (raw), [322:384) pad.
__global__ __launch_bounds__(256) void act_kernel(const unsigned short* __restrict__ qkvb,
                                                  unsigned short* __restrict__ act) {
  int gw = blockIdx.x * 4 + (threadIdx.x >> 6);
  int l = threadIdx.x & 63;
  int m = gw >> 3, hh = gw & 7;
  int t = m >> 3, b = m & 7;
  const unsigned short* src = qkvb + (size_t)m * PROJ + hh * SEG;
  float fq = bf2f(src[l]);
  float fk = bf2f(src[64 + l]);
  float fr = bf2f(src[192 + l]);
  float mq = fq, mk = fk, mr = fr;
#pragma unroll
  for (int o = 32; o; o >>= 1) {
    mq = fmaxf(mq, __shfl_xor(mq, o));
    mk = fmaxf(mk, __shfl_xor(mk, o));
    mr = fmaxf(mr, __shfl_xor(mr, o));
  }
  float eq = __expf(fq - mq), ek = __expf(fk - mk), er = __expf(fr - mr);
  float sq = eq, sk = ek, sr = er;
#pragma unroll
  for (int o = 32; o; o >>= 1) {
    sq += __shfl_xor(sq, o);
    sk += __shfl_xor(sk, o);
    sr += __shfl_xor(sr, o);
  }
  int bh = b * 8 + hh;
  unsigned short* dst = act + ((size_t)bh * S_LEN + t) * RST;
  dst[l] = f2bf(eq * __builtin_amdgcn_rcpf(sq));
  dst[64 + l] = f2bf(ek * __builtin_amdgcn_rcpf(sk));
  dst[128 + l] = f2bf(er * __builtin_amdgcn_rcpf(sr));
  dst[192 + l] = src[128 + l];  // v: raw bf16 copy (no extra rounding)
  dst[256 + l] = src[256 + l];  // rv: raw bf16 copy
  if (l < 2) dst[320 + l] = src[320 + l];  // beta/rbeta logits raw; sigmoid in scan
}

// ---------------- scan: async producer/consumer, bf16 LDS staging ----------------
// Block = 128 threads = 2 waves per (b,h). Wave0 (producer): stages act chunks via
// global_load_lds (6x1KB slices), runs the delta-rule W-scan, deposits z (f32) into a
// 4-chunk LDS ring, publishes per-chunk flags. Wave1 (consumer): polls the flag once
// per chunk, runs the recurrent R-scan. Protocol identical to the verified round-4
// kernel. Delta vs round-4: all vectors staged/broadcast as bf16 (k/q/rk 8xb128 each
// instead of 16, ehb 8xb128), converted to f32 in flight (1 VALU/elem); W/R state,
// z-ring, and all accumulation stay f32. DS ops/step/CU ~45 vs 68 -> attacks the
// shared-LDS-pipe serialization identified from R3/R4 step-time arithmetic.
__global__ __launch_bounds__(128, 1) void scan_kernel(const unsigned short* __restrict__ act,
                                                      unsigned short* __restrict__ hs) {
  int bh = blockIdx.x;
  int b = bh >> 3, hh = bh & 7;
  int tid = threadIdx.x, l = tid & 63, w = tid >> 6;

  __shared__ __align__(16) unsigned short stage[4][CHUNK * RST];  // 24576 B
  __shared__ __align__(16) float zring[4][CHUNK][64];             // 8192 B
  __shared__ __align__(16) unsigned short ehb[64];                // bf16 eh broadcast
  __shared__ int flags[16];  // [0]=w0done (chunks), [8]=w1done (chunks)

  volatile int* w0done = &flags[0];
  volatile int* w1done = &flags[8];

  const char* abase = (const char*)(act + (size_t)bh * S_LEN * RST);

  if (tid == 0) { flags[0] = 0; flags[8] = 0; }
  if (w) ehb[l] = 0x3F80;  // bf16 1.0: softmax(h0=0) numerators -> uniform
  if (w == 0) {
    // stage chunk 0 (6 x 1KB slices)
#pragma unroll
    for (int i = 0; i < 6; i++)
      gl_lds16(abase + (size_t)i * 1024 + l * 16, (char*)&stage[0][0] + i * 1024);
  }
  __syncthreads();  // flags/ehb init visible; drains wave0's chunk-0 staging too

  f32x4 M[16];
#pragma unroll
  for (int j = 0; j < 16; j++) M[j] = (f32x4){0.f, 0.f, 0.f, 0.f};
  const f32x4 z4 = {0.f, 0.f, 0.f, 0.f};

  if (w == 0) {
    // ================= producer: W-scan =================
    for (int c = 0; c < NCH; c++) {
      // back-pressure: staging into slot (c+1)&3 overwrites chunk c-3
      if (c >= 3) {
        while (*w1done < c - 2) __builtin_amdgcn_s_sleep(2);
      }
      if (c + 1 < NCH) {
        const char* nb = abase + (size_t)(c + 1) * CBB;
        char* sb = (char*)&stage[(c + 1) & 3][0];
#pragma unroll
        for (int i = 0; i < 6; i++)
          gl_lds16(nb + (size_t)i * 1024 + l * 16, sb + i * 1024);
        asm volatile("s_waitcnt vmcnt(6)" ::: "memory");  // chunk c's staging done
      } else {
        asm volatile("s_waitcnt vmcnt(0)" ::: "memory");
      }
      const unsigned short* cb = &stage[c & 3][0];
      float* zc = &zring[c & 3][0][0];
#pragma unroll
      for (int s = 0; s < CHUNK; s++) {
        const unsigned short* r = cb + s * RST;
        float cv = bf2f(r[192 + l]);   // v_t[l]
        float blog = bf2f(r[320]);     // beta logit (broadcast)
        // pass-1: vold = M.k ; k kept as bf16 words in regs for pass-2 reconvert
        uint4 kw[8];
#pragma unroll
        for (int j = 0; j < 8; j++) kw[j] = *(const uint4*)(r + 64 + j * 8);
        f32x4 a0 = z4, a1 = z4, a2 = z4, a3 = z4;
#pragma unroll
        for (int j = 0; j < 8; j += 2) {
          f32x4 k0, k1, k2, k3;
          cvt8(kw[j], &k0, &k1);
          cvt8(kw[j + 1], &k2, &k3);
          a0 += M[2 * j] * k0;
          a1 += M[2 * j + 1] * k1;
          a2 += M[2 * j + 2] * k2;
          a3 += M[2 * j + 3] * k3;
        }
        f32x4 vo = (a0 + a1) + (a2 + a3);
        float vold = (vo.x + vo.y) + (vo.z + vo.w);
        float bt = __builtin_amdgcn_rcpf(1.f + __expf(-blog));
        float coef = bt * (cv - vold);
        f32x4 c4 = {coef, coef, coef, coef};
        // pass-2: fused W += coef*k, z = W.q (q read from LDS, k reconverted from regs)
        a0 = a1 = a2 = a3 = z4;
#pragma unroll
        for (int j = 0; j < 8; j += 2) {
          uint4 qw0 = *(const uint4*)(r + j * 8);
          uint4 qw1 = *(const uint4*)(r + (j + 1) * 8);
          f32x4 q0, q1, q2, q3, k0, k1, k2, k3;
          cvt8(qw0, &q0, &q1);
          cvt8(qw1, &q2, &q3);
          cvt8(kw[j], &k0, &k1);
          cvt8(kw[j + 1], &k2, &k3);
          M[2 * j] += c4 * k0;         a0 += M[2 * j] * q0;
          M[2 * j + 1] += c4 * k1;     a1 += M[2 * j + 1] * q1;
          M[2 * j + 2] += c4 * k2;     a2 += M[2 * j + 2] * q2;
          M[2 * j + 3] += c4 * k3;     a3 += M[2 * j + 3] * q3;
        }
        vo = (a0 + a1) + (a2 + a3);
        zc[s * 64 + l] = (vo.x + vo.y) + (vo.z + vo.w);
      }
      asm volatile("s_waitcnt lgkmcnt(0)" ::: "memory");  // z writes retired
      *w0done = c + 1;
    }
  } else {
    // ================= consumer: R-scan =================
    unsigned short* hdst = hs + (size_t)b * 512 + hh * 64 + l;
    for (int c = 0; c < NCH; c++) {
      while (*w0done < c + 1) __builtin_amdgcn_s_sleep(2);  // chunk c staged + z ready
      const unsigned short* cb = &stage[c & 3][0];
      const float* zc = &zring[c & 3][0][0];
#pragma unroll
      for (int s = 0; s < CHUNK; s++) {
        const unsigned short* r = cb + s * RST;
        float zv = zc[s * 64 + l];     // issue early; latency hides under matvec
        float cv = bf2f(r[256 + l]);   // rv_t[l]
        float rblog = bf2f(r[321]);    // rbeta logit (broadcast)
        // pass-1: rvold = R.rk ; rk kept as bf16 words in regs
        uint4 kw[8];
#pragma unroll
        for (int j = 0; j < 8; j++) kw[j] = *(const uint4*)(r + 128 + j * 8);
        f32x4 a0 = z4, a1 = z4, a2 = z4, a3 = z4;
#pragma unroll
        for (int j = 0; j < 8; j += 2) {
          f32x4 k0, k1, k2, k3;
          cvt8(kw[j], &k0, &k1);
          cvt8(kw[j + 1], &k2, &k3);
          a0 += M[2 * j] * k0;
          a1 += M[2 * j + 1] * k1;
          a2 += M[2 * j + 2] * k2;
          a3 += M[2 * j + 3] * k3;
        }
        f32x4 vo = (a0 + a1) + (a2 + a3);
        float rvold = (vo.x + vo.y) + (vo.z + vo.w);
        float rb = __builtin_amdgcn_rcpf(1.f + __expf(-rblog));
        float rcoef = rb * (cv - rvold);
        f32x4 c4 = {rcoef, rcoef, rcoef, rcoef};
        // pass-2: fused R += rcoef*rk, hp = R.eh, sm = sum(eh); eh broadcast as bf16
        const uint4* ew = (const uint4*)ehb;
        f32x4 s0 = z4, s1 = z4;
        a0 = a1 = a2 = a3 = z4;
#pragma unroll
        for (int j = 0; j < 8; j += 2) {
          uint4 ew0 = ew[j];
          uint4 ew1 = ew[j + 1];
          f32x4 e0, e1, e2, e3, k0, k1, k2, k3;
          cvt8(ew0, &e0, &e1);
          cvt8(ew1, &e2, &e3);
          cvt8(kw[j], &k0, &k1);
          cvt8(kw[j + 1], &k2, &k3);
          M[2 * j] += c4 * k0;         a0 += M[2 * j] * e0;       s0 += e0;
          M[2 * j + 1] += c4 * k1;     a1 += M[2 * j + 1] * e1;   s1 += e1;
          M[2 * j + 2] += c4 * k2;     a2 += M[2 * j + 2] * e2;   s0 += e2;
          M[2 * j + 3] += c4 * k3;     a3 += M[2 * j + 3] * e3;   s1 += e3;
        }
        f32x4 ho = (a0 + a1) + (a2 + a3);
        f32x4 so = s0 + s1;
        float hp = (ho.x + ho.y) + (ho.z + ho.w);
        float sm = (so.x + so.y) + (so.z + so.w);
        float h = zv + hp * __builtin_amdgcn_rcpf(sm);
        hdst[(size_t)(c * CHUNK + s) * (BSZ * 512)] = f2bf(h);
        // shift-invariant: exp(h-20) keeps qh = eh/sum exact, guards overflow.
        // same-wave DS ordering makes ehb visible to next step's reads.
        ehb[l] = f2bf(__expf(h - 20.f));
      }
      asm volatile("s_waitcnt lgkmcnt(0)" ::: "memory");  // all chunk-c reads retired
      *w1done = c + 1;
    }
  }
}

extern "C" void kernel_launch(void* const* d_in, const int* in_sizes, int n_in,
                              void* d_out, int out_size, void* d_ws, size_t ws_size,
                              hipStream_t stream) {
  const float* x = (const float*)d_in[0];
  const float* W_slow = (const float*)d_in[1];
  const float* W_out = (const float*)d_in[2];
  const float* gamma = (const float*)d_in[3];
  const float* beta = (const float*)d_in[4];

  char* ws = (char*)d_ws;
  size_t off = 0;
  unsigned short* normed = (unsigned short*)(ws + off); off += (size_t)4096 * 512 * 2;
  unsigned short* Wslow_b = (unsigned short*)(ws + off); off += (size_t)PROJ * 512 * 2;
  unsigned short* Wout_b = (unsigned short*)(ws + off); off += (size_t)512 * 512 * 2;
  unsigned short* qkvb = (unsigned short*)(ws + off); off += (size_t)4096 * PROJ * 2;
  unsigned short* act = (unsigned short*)(ws + off); off += (size_t)64 * S_LEN * RST * 2;
  unsigned short* hsb = normed;  // normed is dead after gemm1; reuse for hs

  hipLaunchKernelGGL(ln_kernel, dim3(1024), dim3(256), 0, stream, x, gamma, beta, normed);
  hipLaunchKernelGGL(cast_kernel, dim3(512), dim3(256), 0, stream, W_slow, Wslow_b, PROJ * 512);
  hipLaunchKernelGGL(cast_kernel, dim3(256), dim3(256), 0, stream, W_out, Wout_b, 512 * 512);
  hipLaunchKernelGGL((gemm_bt<1, 0>), dim3((PROJ + 63) / 64, 4096 / 64), dim3(256), 0, stream,
                     normed, Wslow_b, (void*)qkvb, (const float*)nullptr, 4096, PROJ, 512);
  hipLaunchKernelGGL(act_kernel, dim3(8192), dim3(256), 0, stream, qkvb, act);
  hipLaunchKernelGGL(scan_kernel, dim3(64), dim3(128), 0, stream, act, hsb);
  hipLaunchKernelGGL((gemm_bt<0, 1>), dim3(512 / 64, 4096 / 64), dim3(256), 0, stream,
                     hsb, Wout_b, d_out, x, 4096, 512, 512);
}

// Round 11
// 402.215 us; speedup vs baseline: 1.4666x; 1.2200x over previous
//
#include <hip/hip_runtime.h>

#define S_LEN 512
#define BSZ 8
#define NH 8
#define HD 64
#define IN_DIM 512
#define PROJ 2576   // NH*(5*HD+2)
#define SEG 322     // per-head: 5*64+2
#define AST 352     // act row stride f32: q64,k64,rk64,v64,rv64,beta,rbeta,pad -> 8 rows = 11*1024B
#define CHUNK 8
#define NCH 64      // 512/CHUNK
#define CB (CHUNK * AST * 4)  // 11264 bytes per chunk

typedef __attribute__((ext_vector_type(8))) __bf16 bf16x8;
typedef __attribute__((ext_vector_type(4))) float f32x4;

static __device__ __forceinline__ unsigned short f2bf(float f) {
  unsigned u = __float_as_uint(f);
  unsigned r = (u + 0x7fffu + ((u >> 16) & 1u)) >> 16;
  return (unsigned short)r;
}
static __device__ __forceinline__ float bf2f(unsigned short s) {
  return __uint_as_float(((unsigned)s) << 16);
}

static __device__ __forceinline__ void gl_lds16(const void* g, void* l) {
  __builtin_amdgcn_global_load_lds(
      (const __attribute__((address_space(1))) unsigned int*)g,
      (__attribute__((address_space(3))) unsigned int*)l, 16, 0, 0);
}

// ---------------- LayerNorm: x (4096x512 f32) -> normed bf16 ----------------
__global__ __launch_bounds__(256) void ln_kernel(const float* __restrict__ x,
                                                 const float* __restrict__ gamma,
                                                 const float* __restrict__ beta,
                                                 unsigned short* __restrict__ out) {
  int wave = threadIdx.x >> 6, lane = threadIdx.x & 63;
  int row = blockIdx.x * 4 + wave;
  const float* xr = x + (size_t)row * IN_DIM + lane * 8;
  float4 a = *(const float4*)xr;
  float4 b = *(const float4*)(xr + 4);
  float vals[8] = {a.x, a.y, a.z, a.w, b.x, b.y, b.z, b.w};
  float s = 0.f, ss = 0.f;
#pragma unroll
  for (int i = 0; i < 8; i++) { s += vals[i]; ss += vals[i] * vals[i]; }
#pragma unroll
  for (int o = 32; o; o >>= 1) { s += __shfl_xor(s, o); ss += __shfl_xor(ss, o); }
  float mu = s * (1.f / 512.f);
  float var = ss * (1.f / 512.f) - mu * mu;
  float rstd = rsqrtf(var + 1e-5f);
  const float* g = gamma + lane * 8;
  const float* be = beta + lane * 8;
  float4 g1 = *(const float4*)g, g2 = *(const float4*)(g + 4);
  float4 b1 = *(const float4*)be, b2 = *(const float4*)(be + 4);
  float gs[8] = {g1.x, g1.y, g1.z, g1.w, g2.x, g2.y, g2.z, g2.w};
  float bs[8] = {b1.x, b1.y, b1.z, b1.w, b2.x, b2.y, b2.z, b2.w};
  union { unsigned short u[8]; uint4 v; } pk;
#pragma unroll
  for (int i = 0; i < 8; i++) pk.u[i] = f2bf((vals[i] - mu) * rstd * gs[i] + bs[i]);
  *(uint4*)(out + (size_t)row * IN_DIM + lane * 8) = pk.v;
}

// ---------------- generic f32 -> bf16 cast ----------------
__global__ void cast_kernel(const float* __restrict__ in, unsigned short* __restrict__ out, int n) {
  int i = blockIdx.x * blockDim.x + threadIdx.x;
  int st = gridDim.x * blockDim.x;
  for (; i < n; i += st) out[i] = f2bf(in[i]);
}

// ---------------- GEMM 128x128 tile (m97-style): C[m][n] = sum_k A[m][k]*B[n][k] ----------------
// 256 threads = 4 waves in 2x2; each wave owns a 64x64 quadrant (4x4 frags of 16x16x32).
// LDS staged via global_load_lds width-16 (linear [128][32] bf16 tiles). B rows clamped
// at the staging source (glds cannot mask); C stores masked at gn<N. Fragment/output
// mapping mirrors the session's verified 64^2 kernel exactly.
template <int BF16_OUT, int RESID>
__global__ __launch_bounds__(256) void gemm128(const unsigned short* __restrict__ A,
                                               const unsigned short* __restrict__ B,
                                               void* __restrict__ Cout,
                                               const float* __restrict__ resid,
                                               int M, int N, int K) {
  __shared__ __align__(16) unsigned short As[128 * 32];
  __shared__ __align__(16) unsigned short Bs[128 * 32];
  int tid = threadIdx.x;
  int lane = tid & 63, w = tid >> 6;
  int wr = w >> 1, wc = w & 1;
  int m0 = blockIdx.y * 128, n0 = blockIdx.x * 128;

  // staging: each wave fills 2x 1KB slices (16 rows each) of As and Bs
  int r0 = (w * 2) * 16 + (lane >> 2);
  int r1 = (w * 2 + 1) * 16 + (lane >> 2);
  int kq = (lane & 3) * 8;
  const unsigned short* A0 = A + (size_t)(m0 + r0) * K + kq;
  const unsigned short* A1 = A + (size_t)(m0 + r1) * K + kq;
  int bn0 = n0 + r0; if (bn0 > N - 1) bn0 = N - 1;
  int bn1 = n0 + r1; if (bn1 > N - 1) bn1 = N - 1;
  const unsigned short* B0 = B + (size_t)bn0 * K + kq;
  const unsigned short* B1 = B + (size_t)bn1 * K + kq;
  char* asb0 = (char*)As + (w * 2) * 1024;
  char* asb1 = (char*)As + (w * 2 + 1) * 1024;
  char* bsb0 = (char*)Bs + (w * 2) * 1024;
  char* bsb1 = (char*)Bs + (w * 2 + 1) * 1024;

  f32x4 acc[4][4];
#pragma unroll
  for (int i = 0; i < 4; i++)
#pragma unroll
    for (int j = 0; j < 4; j++) acc[i][j] = (f32x4){0.f, 0.f, 0.f, 0.f};

  int q = lane >> 4, m16 = lane & 15;
  for (int k0 = 0; k0 < K; k0 += 32) {
    gl_lds16(A0 + k0, asb0);
    gl_lds16(A1 + k0, asb1);
    gl_lds16(B0 + k0, bsb0);
    gl_lds16(B1 + k0, bsb1);
    asm volatile("s_waitcnt vmcnt(0)" ::: "memory");
    __syncthreads();
    bf16x8 af[4], bfv[4];
#pragma unroll
    for (int f = 0; f < 4; f++)
      af[f] = *(const bf16x8*)&As[(wr * 64 + f * 16 + m16) * 32 + q * 8];
#pragma unroll
    for (int f = 0; f < 4; f++)
      bfv[f] = *(const bf16x8*)&Bs[(wc * 64 + f * 16 + m16) * 32 + q * 8];
#pragma unroll
    for (int fa = 0; fa < 4; fa++)
#pragma unroll
      for (int fb = 0; fb < 4; fb++)
        acc[fa][fb] = __builtin_amdgcn_mfma_f32_16x16x32_bf16(af[fa], bfv[fb], acc[fa][fb], 0, 0, 0);
    __syncthreads();
  }

#pragma unroll
  for (int fa = 0; fa < 4; fa++) {
#pragma unroll
    for (int fb = 0; fb < 4; fb++) {
#pragma unroll
      for (int rr = 0; rr < 4; rr++) {
        int gm = m0 + wr * 64 + fa * 16 + q * 4 + rr;
        int gn = n0 + wc * 64 + fb * 16 + m16;
        if (gn < N) {
          float v = acc[fa][fb][rr];
          if (BF16_OUT) {
            ((unsigned short*)Cout)[(size_t)gm * N + gn] = f2bf(v);
          } else {
            float o = v;
            if (RESID) o += resid[(size_t)gm * N + gn];
            ((float*)Cout)[(size_t)gm * N + gn] = o;
          }
        }
      }
    }
  }
}

// ---------------- parallel activations -> act stream (f32) ----------------
// One wave per (m = t*8+b, h). act[bh][t][AST]:
// [0:64) q softmax, [64:128) k softmax, [128:192) rk softmax,
// [192:256) v, [256:320) rv, [320] sig(beta), [321] sig(rbeta), [322:352) pad.
__global__ __launch_bounds__(256) void act_kernel(const unsigned short* __restrict__ qkvb,
                                                  float* __restrict__ act) {
  int gw = blockIdx.x * 4 + (threadIdx.x >> 6);
  int l = threadIdx.x & 63;
  int m = gw >> 3, hh = gw & 7;
  int t = m >> 3, b = m & 7;
  const unsigned short* src = qkvb + (size_t)m * PROJ + hh * SEG;
  float fq = bf2f(src[l]);
  float fk = bf2f(src[64 + l]);
  float fv = bf2f(src[128 + l]);
  float fr = bf2f(src[192 + l]);
  float frv = bf2f(src[256 + l]);
  float mq = fq, mk = fk, mr = fr;
#pragma unroll
  for (int o = 32; o; o >>= 1) {
    mq = fmaxf(mq, __shfl_xor(mq, o));
    mk = fmaxf(mk, __shfl_xor(mk, o));
    mr = fmaxf(mr, __shfl_xor(mr, o));
  }
  float eq = __expf(fq - mq), ek = __expf(fk - mk), er = __expf(fr - mr);
  float sq = eq, sk = ek, sr = er;
#pragma unroll
  for (int o = 32; o; o >>= 1) {
    sq += __shfl_xor(sq, o);
    sk += __shfl_xor(sk, o);
    sr += __shfl_xor(sr, o);
  }
  int bh = b * 8 + hh;
  float* dst = act + ((size_t)bh * S_LEN + t) * AST;
  dst[l] = eq * __builtin_amdgcn_rcpf(sq);
  dst[64 + l] = ek * __builtin_amdgcn_rcpf(sk);
  dst[128 + l] = er * __builtin_amdgcn_rcpf(sr);
  dst[192 + l] = fv;
  dst[256 + l] = frv;
  if (l < 2) {
    float xv = bf2f(src[320 + l]);
    dst[320 + l] = __builtin_amdgcn_rcpf(1.f + __expf(-xv));
  }
}

// ---------------- scan: async producer/consumer waves (verified round-4 kernel) ----------------
// Block = 128 threads = 2 waves per (b,h). Wave0 (producer): stages act chunks via
// global_load_lds, runs the delta-rule W-scan, deposits z into a 4-chunk LDS ring,
// publishes per-chunk flags. Wave1 (consumer): polls the flag once per chunk (8 steps),
// runs the recurrent R-scan. Byte-identical restore of the 276 us round-4 kernel.
__global__ __launch_bounds__(128, 1) void scan_kernel(const float* __restrict__ act,
                                                      unsigned short* __restrict__ hs) {
  int bh = blockIdx.x;
  int b = bh >> 3, hh = bh & 7;
  int tid = threadIdx.x, l = tid & 63, w = tid >> 6;

  __shared__ __align__(16) float stage[4][CHUNK * AST];
  __shared__ __align__(16) float zring[4][CHUNK][64];
  __shared__ __align__(16) float ehb[64];
  __shared__ int flags[16];  // [0]=w0done (chunks), [8]=w1done (chunks)

  volatile int* w0done = &flags[0];
  volatile int* w1done = &flags[8];

  const char* abase = (const char*)(act + (size_t)bh * S_LEN * AST);

  if (tid == 0) { flags[0] = 0; flags[8] = 0; }
  if (w) ehb[l] = 1.f;  // softmax(h0=0) numerators -> uniform
  if (w == 0) {
    // stage chunk 0
#pragma unroll
    for (int i = 0; i < 11; i++)
      gl_lds16(abase + (size_t)i * 1024 + l * 16, (char*)&stage[0][0] + i * 1024);
  }
  __syncthreads();  // flags/ehb init visible; drains wave0's chunk-0 staging too

  f32x4 M[16];
#pragma unroll
  for (int j = 0; j < 16; j++) M[j] = (f32x4){0.f, 0.f, 0.f, 0.f};
  const f32x4 z4 = {0.f, 0.f, 0.f, 0.f};

  if (w == 0) {
    // ================= producer: W-scan =================
    for (int c = 0; c < NCH; c++) {
      // back-pressure: staging into slot (c+1)&3 overwrites chunk c-3
      if (c >= 3) {
        while (*w1done < c - 2) __builtin_amdgcn_s_sleep(2);
      }
      if (c + 1 < NCH) {
        const char* nb = abase + (size_t)(c + 1) * CB;
        char* sb = (char*)&stage[(c + 1) & 3][0];
#pragma unroll
        for (int i = 0; i < 11; i++)
          gl_lds16(nb + (size_t)i * 1024 + l * 16, sb + i * 1024);
        asm volatile("s_waitcnt vmcnt(11)" ::: "memory");  // chunk c's staging done
      } else {
        asm volatile("s_waitcnt vmcnt(0)" ::: "memory");
      }
      const float* cb = &stage[c & 3][0];
      float* zc = &zring[c & 3][0][0];
#pragma unroll
      for (int s = 0; s < CHUNK; s++) {
        const float* stf = cb + s * AST;
        const f32x4* st4 = (const f32x4*)stf;
        // ---- vold = W.k; fused W += coef*k, z = W.q ----
        float cv = stf[192 + l];
        f32x4 kk[16];
#pragma unroll
        for (int j = 0; j < 16; j++) kk[j] = st4[16 + j];  // k
        f32x4 a0 = z4, a1 = z4, a2 = z4, a3 = z4;
#pragma unroll
        for (int j = 0; j < 16; j += 4) {
          a0 += M[j] * kk[j];
          a1 += M[j + 1] * kk[j + 1];
          a2 += M[j + 2] * kk[j + 2];
          a3 += M[j + 3] * kk[j + 3];
        }
        f32x4 vo = (a0 + a1) + (a2 + a3);
        float vold = (vo.x + vo.y) + (vo.z + vo.w);
        float bt = stf[320];
        float coef = bt * (cv - vold);
        f32x4 c4 = {coef, coef, coef, coef};
        a0 = a1 = a2 = a3 = z4;
#pragma unroll
        for (int j = 0; j < 16; j += 4) {
          M[j] += c4 * kk[j];         a0 += M[j] * st4[j];
          M[j + 1] += c4 * kk[j + 1]; a1 += M[j + 1] * st4[j + 1];
          M[j + 2] += c4 * kk[j + 2]; a2 += M[j + 2] * st4[j + 2];
          M[j + 3] += c4 * kk[j + 3]; a3 += M[j + 3] * st4[j + 3];
        }
        vo = (a0 + a1) + (a2 + a3);
        zc[s * 64 + l] = (vo.x + vo.y) + (vo.z + vo.w);
      }
      asm volatile("s_waitcnt lgkmcnt(0)" ::: "memory");  // z writes retired
      *w0done = c + 1;
    }
  } else {
    // ================= consumer: R-scan =================
    unsigned short* hdst = hs + (size_t)b * 512 + hh * 64 + l;
    for (int c = 0; c < NCH; c++) {
      while (*w0done < c + 1) __builtin_amdgcn_s_sleep(2);  // chunk c staged + z ready
      const float* cb = &stage[c & 3][0];
      const float* zc = &zring[c & 3][0][0];
#pragma unroll
      for (int s = 0; s < CHUNK; s++) {
        const float* stf = cb + s * AST;
        const f32x4* st4 = (const f32x4*)stf;
        float z = zc[s * 64 + l];  // issue early; latency hides under matvec
        // ---- rvold = R.rk; fused R += rcoef*rk, hp = R.eh, sm = sum(eh) ----
        float cv = stf[256 + l];
        f32x4 kk[16];
#pragma unroll
        for (int j = 0; j < 16; j++) kk[j] = st4[32 + j];  // rk
        f32x4 a0 = z4, a1 = z4, a2 = z4, a3 = z4;
#pragma unroll
        for (int j = 0; j < 16; j += 4) {
          a0 += M[j] * kk[j];
          a1 += M[j + 1] * kk[j + 1];
          a2 += M[j + 2] * kk[j + 2];
          a3 += M[j + 3] * kk[j + 3];
        }
        f32x4 vo = (a0 + a1) + (a2 + a3);
        float rvold = (vo.x + vo.y) + (vo.z + vo.w);
        float rb = stf[321];
        float rcoef = rb * (cv - rvold);
        f32x4 c4 = {rcoef, rcoef, rcoef, rcoef};
        const f32x4* e4 = (const f32x4*)ehb;
        f32x4 s0 = z4, s1 = z4, s2v = z4, s3 = z4;
        a0 = a1 = a2 = a3 = z4;
#pragma unroll
        for (int j = 0; j < 16; j += 4) {
          f32x4 e0 = e4[j], e1 = e4[j + 1], e2 = e4[j + 2], e3 = e4[j + 3];
          M[j] += c4 * kk[j];         a0 += M[j] * e0;       s0 += e0;
          M[j + 1] += c4 * kk[j + 1]; a1 += M[j + 1] * e1;   s1 += e1;
          M[j + 2] += c4 * kk[j + 2]; a2 += M[j + 2] * e2;   s2v += e2;
          M[j + 3] += c4 * kk[j + 3]; a3 += M[j + 3] * e3;   s3 += e3;
        }
        f32x4 ho = (a0 + a1) + (a2 + a3);
        f32x4 so = (s0 + s1) + (s2v + s3);
        float hp = (ho.x + ho.y) + (ho.z + ho.w);
        float sm = (so.x + so.y) + (so.z + so.w);
        float h = z + hp * __builtin_amdgcn_rcpf(sm);
        hdst[(size_t)(c * CHUNK + s) * (BSZ * 512)] = f2bf(h);
        // shift-invariant: exp(h-20) keeps qh = eh/sum exact, guards overflow.
        // same-wave DS ordering makes it visible to next step's e4 reads.
        ehb[l] = __expf(h - 20.f);
      }
      asm volatile("s_waitcnt lgkmcnt(0)" ::: "memory");  // all chunk-c reads retired
      *w1done = c + 1;
    }
  }
}

extern "C" void kernel_launch(void* const* d_in, const int* in_sizes, int n_in,
                              void* d_out, int out_size, void* d_ws, size_t ws_size,
                              hipStream_t stream) {
  const float* x = (const float*)d_in[0];
  const float* W_slow = (const float*)d_in[1];
  const float* W_out = (const float*)d_in[2];
  const float* gamma = (const float*)d_in[3];
  const float* beta = (const float*)d_in[4];

  char* ws = (char*)d_ws;
  size_t off = 0;
  unsigned short* normed = (unsigned short*)(ws + off); off += (size_t)4096 * 512 * 2;
  unsigned short* Wslow_b = (unsigned short*)(ws + off); off += (size_t)PROJ * 512 * 2;
  unsigned short* Wout_b = (unsigned short*)(ws + off); off += (size_t)512 * 512 * 2;
  unsigned short* qkvb = (unsigned short*)(ws + off); off += (size_t)4096 * PROJ * 2;
  float* act = (float*)(ws + off); off += (size_t)64 * S_LEN * AST * 4;
  unsigned short* hsb = normed;  // normed is dead after gemm1; reuse for hs

  hipLaunchKernelGGL(ln_kernel, dim3(1024), dim3(256), 0, stream, x, gamma, beta, normed);
  hipLaunchKernelGGL(cast_kernel, dim3(512), dim3(256), 0, stream, W_slow, Wslow_b, PROJ * 512);
  hipLaunchKernelGGL(cast_kernel, dim3(256), dim3(256), 0, stream, W_out, Wout_b, 512 * 512);
  hipLaunchKernelGGL((gemm128<1, 0>), dim3((PROJ + 127) / 128, 4096 / 128), dim3(256), 0, stream,
                     normed, Wslow_b, (void*)qkvb, (const float*)nullptr, 4096, PROJ, 512);
  hipLaunchKernelGGL(act_kernel, dim3(8192), dim3(256), 0, stream, qkvb, act);
  hipLaunchKernelGGL(scan_kernel, dim3(64), dim3(128), 0, stream, act, hsb);
  hipLaunchKernelGGL((gemm128<0, 1>), dim3(512 / 128, 4096 / 128), dim3(256), 0, stream,
                     hsb, Wout_b, d_out, x, 4096, 512, 512);
}